// Round 19
// baseline (485.345 us; speedup 1.0000x reference)
//
#include <hip/hip_runtime.h>

#define B 32
#define C 16
#define H 256
#define W 256
#define HID 128
#define HW (H*W)
#define MROWS 32
#define NMM 4096   // minmax blocks: 32*16*(256/32)

typedef __attribute__((ext_vector_type(8))) _Float16 f16x8;
typedef __attribute__((ext_vector_type(4))) _Float16 f16x4;
typedef __attribute__((ext_vector_type(4))) float f32x4;

// ---- order-preserving float <-> uint key for atomic min/max ----
__device__ __forceinline__ unsigned fkey(float f){
  unsigned u = __float_as_uint(f);
  return (u & 0x80000000u) ? ~u : (u | 0x80000000u);
}
__device__ __forceinline__ float fkeyinv(unsigned k){
  unsigned u = (k & 0x80000000u) ? (k & 0x7FFFFFFFu) : ~k;
  return __uint_as_float(u);
}

// ---- fused prep (weight fragments) + per-channel Sobel min/max ----
// mm layout: [0..15]=gx_min [16..31]=gy_min [32..47]=gx_max [48..63]=gy_max
__global__ __launch_bounds__(64) void k_pm(
    const float* __restrict__ x, const float* __restrict__ w1,
    const float* __restrict__ w2, unsigned* __restrict__ mm,
    _Float16* __restrict__ w1kh, _Float16* __restrict__ w1kl,
    _Float16* __restrict__ w1k1h, _Float16* __restrict__ w1k1l,
    _Float16* __restrict__ w2h)
{
  const int tid = threadIdx.x;
  if (blockIdx.x >= NMM){
    int e = (blockIdx.x - NMM)*64 + tid;
    if (e < 4096){
      // w1 k=0..31, x32 A frags: lane l -> M=l&15, K=8*(l>>4)+j
      int j = e & 7, l = (e >> 3) & 63, ot = e >> 9;
      float v = w1[(16*ot + (l & 15))*48 + 8*(l >> 4) + j];
      _Float16 h = (_Float16)v;
      w1kh[e] = h; w1kl[e] = (_Float16)(v - (float)h);
    } else if (e < 6144){
      // w1 k=32..47, x16 A frags: lane l -> M=l&15, K=4*(l>>4)+j
      int e2 = e - 4096;
      int j = e2 & 3, l = (e2 >> 2) & 63, ot = e2 >> 8;
      float v = w1[(16*ot + (l & 15))*48 + 32 + 4*(l >> 4) + j];
      _Float16 h = (_Float16)v;
      w1k1h[e2] = h; w1k1l[e2] = (_Float16)(v - (float)h);
    } else if (e < 8192){
      // w2 hi-only x32 A frags
      int e2 = e - 6144;
      int j = e2 & 7, l = (e2 >> 3) & 63, s = e2 >> 9;
      w2h[e2] = (_Float16)w2[(l & 15)*128 + 32*s + 8*(l >> 4) + j];
    }
    return;
  }
  int chunk = blockIdx.x & 7, bc = blockIdx.x >> 3, c = bc & 15;
  const float* p = x + (size_t)bc * HW;
  const int j4 = tid * 4;
  const int i0 = chunk * MROWS;

  float Aw[6], Bw[6], Cw[6];
  auto loadrow = [&](int row, float* wv){
    float4 v = *(const float4*)(p + (size_t)row*W + j4);
    float l = __shfl(v.w, tid - 1);
    float r = __shfl(v.x, tid + 1);
    if (tid == 0)  l = 0.f;
    if (tid == 63) r = 0.f;
    wv[0]=l; wv[1]=v.x; wv[2]=v.y; wv[3]=v.z; wv[4]=v.w; wv[5]=r;
  };
  if (i0 > 0) loadrow(i0-1, Aw);
  else { for (int t=0;t<6;++t) Aw[t]=0.f; }
  loadrow(i0, Bw);

  float gxmn = 1e30f, gxmx = -1e30f, gymn = 1e30f, gymx = -1e30f;
  for (int r = 0; r < MROWS; ++r){
    int ipr = i0 + r + 1;
    if (ipr < H) loadrow(ipr, Cw);
    else { for (int t=0;t<6;++t) Cw[t]=0.f; }
    #pragma unroll
    for (int t = 0; t < 4; ++t){
      float gx = (Aw[t+2]-Aw[t] + 2.f*(Bw[t+2]-Bw[t]) + Cw[t+2]-Cw[t]) * 0.125f;
      float gy = (Cw[t]-Aw[t] + 2.f*(Cw[t+1]-Aw[t+1]) + Cw[t+2]-Aw[t+2]) * 0.125f;
      gxmn = fminf(gxmn, gx); gxmx = fmaxf(gxmx, gx);
      gymn = fminf(gymn, gy); gymx = fmaxf(gymx, gy);
    }
    #pragma unroll
    for (int t = 0; t < 6; ++t){ Aw[t] = Bw[t]; Bw[t] = Cw[t]; }
  }
  for (int off = 32; off; off >>= 1){
    gxmn = fminf(gxmn, __shfl_down(gxmn, off));
    gxmx = fmaxf(gxmx, __shfl_down(gxmx, off));
    gymn = fminf(gymn, __shfl_down(gymn, off));
    gymx = fmaxf(gymx, __shfl_down(gymx, off));
  }
  if (tid == 0){
    atomicMin(&mm[c],      fkey(gxmn));
    atomicMin(&mm[16+c],   fkey(gymn));
    atomicMax(&mm[32+c],   fkey(gxmx));
    atomicMax(&mm[48+c],   fkey(gymx));
  }
}

// ---- main: 1 wave / 64 px; LDS-STAGED stencil (TA-relief) ----
// Theory: r12-r18 invariance = TA/L1-issue-bound (~210 vector-mem instrs
// per wave). Staging the x halo tile via 14 coalesced float4 loads cuts
// TA instrs ~4x; stencil taps + epilogue x come from LDS instead.
__global__ __launch_bounds__(64) void k_main(
    const float* __restrict__ x, const float* __restrict__ mrand,
    const unsigned* __restrict__ mm,
    const _Float16* __restrict__ w1kh, const _Float16* __restrict__ w1kl,
    const _Float16* __restrict__ w1k1h, const _Float16* __restrict__ w1k1l,
    const _Float16* __restrict__ w2h, const float* __restrict__ w2f,
    const float* __restrict__ b1,
    float* __restrict__ out, float* __restrict__ alpha_new,
    unsigned char* __restrict__ premask)
{
  // x halo staging: 48 (ch,row) tuples x 72 cols fp32 (cols j0-4 .. j0+67)
  __shared__ __align__(16) float st[48][72];       // 13.8 KB
  // y/h rows: 16 chunks of 16B, XOR-swizzled (phys = chunk ^ (px&15)).
  __shared__ __align__(16) _Float16 yl[64][128];   // 16 KB
  __shared__ float amn_x[16], inv_x[16], amn_y[16], inv_y[16];

  const int tid = threadIdx.x;
  // XCD swizzle (r11-proven: FETCH 242->70 MB)
  const int blk = blockIdx.x;
  const int bswz = (blk & 7)*4096 + (blk >> 3);
  const int quarter = bswz & 3;
  const int rowid = bswz >> 2;                 // b*H + i
  const int i = rowid & 255, b = rowid >> 8;
  const int j0 = quarter << 6;
  const int q = tid >> 4, n16 = tid & 15;

  if (tid < 16){
    int c = tid;
    float mn = fabsf(fkeyinv(mm[c]));
    float mx = fabsf(fkeyinv(mm[32+c]));
    float dv = mn + mx;
    amn_x[c] = mn; inv_x[c] = (dv == 0.f) ? 1.f : 1.f/dv;
    mn = fabsf(fkeyinv(mm[16+c]));
    mx = fabsf(fkeyinv(mm[48+c]));
    dv = mn + mx;
    amn_y[c] = mn; inv_y[c] = (dv == 0.f) ? 1.f : 1.f/dv;
  }
  // single-wave block: LDS ops are program-ordered, no barrier needed

  // ---- stage x tile: 864 float4 slots, 14 coalesced passes ----
  {
    #pragma unroll
    for (int p = 0; p < 14; ++p){
      int s = p*64 + tid;
      if (s < 864){
        int tuple = s / 18;            // 0..47
        int f4    = s - tuple*18;      // 0..17
        int ch    = tuple / 3;
        int dr    = tuple - 3*ch;      // 0,1,2
        int row   = i - 1 + dr;
        int col0  = j0 - 4 + 4*f4;
        float4 v = make_float4(0.f, 0.f, 0.f, 0.f);
        if (row >= 0 && row < H && col0 >= 0 && col0 <= W-4)
          v = *(const float4*)(x + (((size_t)b*C + ch)*H + row)*W + col0);
        *(float4*)&st[tuple][4*f4] = v;
      }
    }
  }

  // ---- stencil from LDS (taps at word w-1..w+1, w = tid+4) ----
  {
    const int j = j0 + tid;
    const int w = tid + 4;
    const int key = tid & 15;
    #pragma unroll
    for (int hp = 0; hp < 2; ++hp){
      float xv[8], lv[8], mv[8];
      #pragma unroll
      for (int cc = 0; cc < 8; ++cc){
        const int c = hp*8 + cc;
        const float* r0 = st[3*c    ];
        const float* r1 = st[3*c + 1];
        const float* r2 = st[3*c + 2];
        float v00 = r0[w-1], v01 = r0[w], v02 = r0[w+1];
        float v10 = r1[w-1], v11 = r1[w], v12 = r1[w+1];
        float v20 = r2[w-1], v21 = r2[w], v22 = r2[w+1];
        float gx = (v02 - v00 + 2.f*(v12 - v10) + v22 - v20) * 0.125f;
        float gy = (v20 - v00 + 2.f*(v21 - v01) + v22 - v02) * 0.125f;
        float gl = (v01 + v10 + v12 + v21 - 4.f*v11) * 0.125f;
        float gxn = (gx + amn_x[c]) * inv_x[c];
        float gyn = (gy + amn_y[c]) * inv_y[c];
        xv[cc] = v11;
        lv[cc] = gl;
        mv[cc] = sqrtf(gxn*gxn + gyn*gyn);
        if (hp == 0 && cc == 3){
          float pre3 = fmaxf(fmaxf(fmaxf(v00,v01),fmaxf(v02,v10)),
                       fmaxf(fmaxf(v11,v12),fmaxf(fmaxf(v20,v21),v22)));
          premask[(size_t)b*HW + (size_t)i*W + j] = (pre3 > 0.1f) ? 1 : 0;
        }
      }
      f16x8 vh, vl;
      #pragma unroll
      for (int e = 0; e < 8; ++e){ _Float16 h=(_Float16)xv[e]; vh[e]=h; vl[e]=(_Float16)(xv[e]-(float)h); }
      *(f16x8*)&yl[tid][((hp     ) ^ key)*8] = vh;
      *(f16x8*)&yl[tid][((6+hp   ) ^ key)*8] = vl;
      #pragma unroll
      for (int e = 0; e < 8; ++e){ _Float16 h=(_Float16)lv[e]; vh[e]=h; vl[e]=(_Float16)(lv[e]-(float)h); }
      *(f16x8*)&yl[tid][((2+hp   ) ^ key)*8] = vh;
      *(f16x8*)&yl[tid][((8+hp   ) ^ key)*8] = vl;
      #pragma unroll
      for (int e = 0; e < 8; ++e){ _Float16 h=(_Float16)mv[e]; vh[e]=h; vl[e]=(_Float16)(mv[e]-(float)h); }
      *(f16x8*)&yl[tid][((4+hp   ) ^ key)*8] = vh;
      *(f16x8*)&yl[tid][((10+hp  ) ^ key)*8] = vl;
    }
  }

  // ---- resident fragments: A1 x32 hi/lo (64 VGPR) + A2 hi (16 VGPR) ----
  f16x8 A1h[8], A1l[8];
  #pragma unroll
  for (int ot = 0; ot < 8; ++ot){
    A1h[ot] = *(const f16x8*)(w1kh + ot*512 + tid*8);
    A1l[ot] = *(const f16x8*)(w1kl + ot*512 + tid*8);
  }
  f16x8 A2h[4];
  #pragma unroll
  for (int s = 0; s < 4; ++s)
    A2h[s] = *(const f16x8*)(w2h + s*512 + tid*8);

  const size_t rowbase = (size_t)b*C*HW + (size_t)i*W;
  const size_t abase   = (size_t)b*HW + (size_t)i*W;
  const float* mr_row  = mrand + abase + j0;
  const float* w2r3    = w2f + 3*HID;

  // ---- 4 groups of 16 pixels ----
  #pragma unroll 1
  for (int g = 0; g < 4; ++g){
    const int pl = g*16 + n16;                // local pixel / LDS row
    const int key = n16;                      // = pl & 15
    _Float16* yr = yl[pl];
    f16x8 Bh0 = *(const f16x8*)&yr[(( q          ) ^ key)*8];
    f16x8 Bl0 = *(const f16x8*)&yr[(( 6+q        ) ^ key)*8];
    f16x4 Bh1 = *(const f16x4*)(&yr[(( 4+(q>>1)  ) ^ key)*8] + 4*(q&1));
    f16x4 Bl1 = *(const f16x4*)(&yr[((10+(q>>1)  ) ^ key)*8] + 4*(q&1));

    // GEMM1: h = relu(w1*y + b1); 4-product hi/lo over K=32 (x32) + K=16 (x16)
    // h written straight back into the (now dead) LDS row as the transpose.
    float partial3 = 0.f;
    #pragma unroll
    for (int ot = 0; ot < 8; ++ot){
      f16x4 A1h1 = *(const f16x4*)(w1k1h + ot*256 + tid*4);   // L1-hot 4KB
      f16x4 A1l1 = *(const f16x4*)(w1k1l + ot*256 + tid*4);
      f32x4 acc = *(const f32x4*)(b1 + 16*ot + 4*q);          // L1-hot
      acc = __builtin_amdgcn_mfma_f32_16x16x32_f16(A1h[ot], Bh0, acc, 0, 0, 0);
      acc = __builtin_amdgcn_mfma_f32_16x16x32_f16(A1h[ot], Bl0, acc, 0, 0, 0);
      acc = __builtin_amdgcn_mfma_f32_16x16x32_f16(A1l[ot], Bh0, acc, 0, 0, 0);
      acc = __builtin_amdgcn_mfma_f32_16x16x32_f16(A1l[ot], Bl0, acc, 0, 0, 0);
      acc = __builtin_amdgcn_mfma_f32_16x16x16f16(A1h1, Bh1, acc, 0, 0, 0);
      acc = __builtin_amdgcn_mfma_f32_16x16x16f16(A1h1, Bl1, acc, 0, 0, 0);
      acc = __builtin_amdgcn_mfma_f32_16x16x16f16(A1l1, Bh1, acc, 0, 0, 0);
      acc = __builtin_amdgcn_mfma_f32_16x16x16f16(A1l1, Bl1, acc, 0, 0, 0);
      float h0 = fmaxf(acc[0],0.f), h1 = fmaxf(acc[1],0.f);
      float h2 = fmaxf(acc[2],0.f), h3 = fmaxf(acc[3],0.f);
      // exact fp32 alpha path: partial dot with w2 row 3 (L1-hot 512B)
      f32x4 w3 = *(const f32x4*)(w2r3 + 16*ot + 4*q);
      partial3 = fmaf(w3[0],h0, fmaf(w3[1],h1, fmaf(w3[2],h2, fmaf(w3[3],h3, partial3))));
      // h[o=16ot+4q+r][px=pl] -> row pl, chunk (2ot+(q>>1))^key, half q&1
      f16x4 hv;
      hv[0]=(_Float16)h0; hv[1]=(_Float16)h1; hv[2]=(_Float16)h2; hv[3]=(_Float16)h3;
      *(f16x4*)(&yr[(((2*ot + (q>>1)) ^ key)*8) + 4*(q&1)]) = hv;
    }
    // reduce partial3 across the 4 q-groups
    partial3 += __shfl_xor(partial3, 16);
    partial3 += __shfl_xor(partial3, 32);      // dx[3] for pixel pl, all lanes

    // GEMM2 (hi-only): dx = w2h * h; B read back from the transposed row
    f32x4 d2 = {0.f, 0.f, 0.f, 0.f};
    #pragma unroll
    for (int s = 0; s < 4; ++s){
      f16x8 B2 = *(const f16x8*)&yr[((4*s + q) ^ key)*8];
      d2 = __builtin_amdgcn_mfma_f32_16x16x32_f16(A2h[s], B2, d2, 0, 0, 0);
    }

    // epilogue: exact fp32 x from the staging tile (zero global loads)
    const float fire = (mr_row[pl] <= 0.5f) ? 1.f : 0.f;
    float a3v = 0.f;
    #pragma unroll
    for (int r = 0; r < 4; ++r){
      const int c = 4*q + r;
      const float xv = st[3*c + 1][pl + 4];
      const float dxv = (c == 3) ? partial3 : d2[r];
      const float val = xv + dxv*fire;
      out[rowbase + (size_t)c*HW + (j0 + pl)] = val;
      if (c == 3) a3v = val;
    }
    if (q == 0) alpha_new[abase + j0 + pl] = a3v;
  }
}

// ---- life: pre-mask (from k_main) AND pooled(alpha_new) > 0.1 ----
__global__ __launch_bounds__(256) void k_life(
    const float* __restrict__ alpha_new,
    const unsigned char* __restrict__ premask,
    float* __restrict__ out)
{
  __shared__ float lds[258];
  const int i = blockIdx.x & 255, b = blockIdx.x >> 8;
  const int j = threadIdx.x;
  const float* an = alpha_new + (size_t)b*HW;
  float m = an[(size_t)i*W + j];
  if (i > 0)   m = fmaxf(m, an[(size_t)(i-1)*W + j]);
  if (i < 255) m = fmaxf(m, an[(size_t)(i+1)*W + j]);
  if (j == 0){ lds[0] = 0.f; lds[257] = 0.f; }
  lds[j+1] = m;
  __syncthreads();
  float pooled = fmaxf(fmaxf(lds[j], lds[j+1]), lds[j+2]);
  bool life = (premask[(size_t)b*HW + (size_t)i*W + j] != 0) && (pooled > 0.1f);
  if (!life){
    size_t px = (size_t)b*C*HW + (size_t)i*W + j;
    #pragma unroll
    for (int c = 0; c < 16; ++c) out[px + (size_t)c*HW] = 0.f;
  }
}

extern "C" void kernel_launch(void* const* d_in, const int* in_sizes, int n_in,
                              void* d_out, int out_size, void* d_ws, size_t ws_size,
                              hipStream_t stream) {
  const float* x  = (const float*)d_in[0];
  const float* w1 = (const float*)d_in[1];
  const float* b1 = (const float*)d_in[2];
  const float* w2 = (const float*)d_in[3];
  const float* mr = (const float*)d_in[4];

  char* ws = (char*)d_ws;
  unsigned* mm          = (unsigned*)ws;                          // 256 B
  float* alpha_n        = (float*)(ws + 256);                     // 8 MB
  unsigned char* pmask  = (unsigned char*)(ws + 256 + 8388608);   // 2 MB
  char* wb              = ws + 256 + 8388608 + 2097152;
  _Float16* w1kh  = (_Float16*)(wb);                              // 8 KB
  _Float16* w1kl  = (_Float16*)(wb + 8192);                       // 8 KB
  _Float16* w1k1h = (_Float16*)(wb + 16384);                      // 4 KB
  _Float16* w1k1l = (_Float16*)(wb + 20480);                      // 4 KB
  _Float16* w2h   = (_Float16*)(wb + 24576);                      // 4 KB
  float* out = (float*)d_out;

  (void)hipMemsetAsync(mm, 0xFF, 128, stream);                // mins -> +inf key
  (void)hipMemsetAsync((char*)mm + 128, 0x00, 128, stream);   // maxs -> -inf key
  k_pm  <<<NMM + 128, 64, 0, stream>>>(x, w1, w2, mm, w1kh, w1kl,
                                       w1k1h, w1k1l, w2h);
  k_main<<<B*H*4, 64, 0, stream>>>(x, mr, mm, w1kh, w1kl, w1k1h, w1k1l,
                                   w2h, w2, b1, out, alpha_n, pmask);
  k_life<<<B*H, 256, 0, stream>>>(alpha_n, pmask, out);
}

// Round 20
// 335.756 us; speedup vs baseline: 1.4455x; 1.4455x over previous
//
#include <hip/hip_runtime.h>

#define B 32
#define C 16
#define H 256
#define W 256
#define HID 128
#define HW (H*W)
#define MROWS 32
#define NMM 4096   // minmax blocks: 32*16*(256/32)

typedef __attribute__((ext_vector_type(8))) _Float16 f16x8;
typedef __attribute__((ext_vector_type(4))) _Float16 f16x4;
typedef __attribute__((ext_vector_type(4))) float f32x4;

// ---- order-preserving float <-> uint key for atomic min/max ----
__device__ __forceinline__ unsigned fkey(float f){
  unsigned u = __float_as_uint(f);
  return (u & 0x80000000u) ? ~u : (u | 0x80000000u);
}
__device__ __forceinline__ float fkeyinv(unsigned k){
  unsigned u = (k & 0x80000000u) ? (k & 0x7FFFFFFFu) : ~k;
  return __uint_as_float(u);
}

// ---- fused prep (weight fragments) + per-channel Sobel min/max ----
// mm layout: [0..15]=gx_min [16..31]=gy_min [32..47]=gx_max [48..63]=gy_max
__global__ __launch_bounds__(64) void k_pm(
    const float* __restrict__ x, const float* __restrict__ w1,
    const float* __restrict__ w2, unsigned* __restrict__ mm,
    _Float16* __restrict__ w1kh, _Float16* __restrict__ w1kl,
    _Float16* __restrict__ w1k1h, _Float16* __restrict__ w1k1l,
    _Float16* __restrict__ w2h)
{
  const int tid = threadIdx.x;
  if (blockIdx.x >= NMM){
    int e = (blockIdx.x - NMM)*64 + tid;
    if (e < 4096){
      // w1 k=0..31, x32 A frags: lane l -> M=l&15, K=8*(l>>4)+j
      int j = e & 7, l = (e >> 3) & 63, ot = e >> 9;
      float v = w1[(16*ot + (l & 15))*48 + 8*(l >> 4) + j];
      _Float16 h = (_Float16)v;
      w1kh[e] = h; w1kl[e] = (_Float16)(v - (float)h);
    } else if (e < 6144){
      // w1 k=32..47, x16 A frags: lane l -> M=l&15, K=4*(l>>4)+j
      int e2 = e - 4096;
      int j = e2 & 3, l = (e2 >> 2) & 63, ot = e2 >> 8;
      float v = w1[(16*ot + (l & 15))*48 + 32 + 4*(l >> 4) + j];
      _Float16 h = (_Float16)v;
      w1k1h[e2] = h; w1k1l[e2] = (_Float16)(v - (float)h);
    } else if (e < 8192){
      // w2 hi-only x32 A frags
      int e2 = e - 6144;
      int j = e2 & 7, l = (e2 >> 3) & 63, s = e2 >> 9;
      w2h[e2] = (_Float16)w2[(l & 15)*128 + 32*s + 8*(l >> 4) + j];
    }
    return;
  }
  int chunk = blockIdx.x & 7, bc = blockIdx.x >> 3, c = bc & 15;
  const float* p = x + (size_t)bc * HW;
  const int j4 = tid * 4;
  const int i0 = chunk * MROWS;

  float Aw[6], Bw[6], Cw[6];
  auto loadrow = [&](int row, float* wv){
    float4 v = *(const float4*)(p + (size_t)row*W + j4);
    float l = __shfl(v.w, tid - 1);
    float r = __shfl(v.x, tid + 1);
    if (tid == 0)  l = 0.f;
    if (tid == 63) r = 0.f;
    wv[0]=l; wv[1]=v.x; wv[2]=v.y; wv[3]=v.z; wv[4]=v.w; wv[5]=r;
  };
  if (i0 > 0) loadrow(i0-1, Aw);
  else { for (int t=0;t<6;++t) Aw[t]=0.f; }
  loadrow(i0, Bw);

  float gxmn = 1e30f, gxmx = -1e30f, gymn = 1e30f, gymx = -1e30f;
  for (int r = 0; r < MROWS; ++r){
    int ipr = i0 + r + 1;
    if (ipr < H) loadrow(ipr, Cw);
    else { for (int t=0;t<6;++t) Cw[t]=0.f; }
    #pragma unroll
    for (int t = 0; t < 4; ++t){
      float gx = (Aw[t+2]-Aw[t] + 2.f*(Bw[t+2]-Bw[t]) + Cw[t+2]-Cw[t]) * 0.125f;
      float gy = (Cw[t]-Aw[t] + 2.f*(Cw[t+1]-Aw[t+1]) + Cw[t+2]-Aw[t+2]) * 0.125f;
      gxmn = fminf(gxmn, gx); gxmx = fmaxf(gxmx, gx);
      gymn = fminf(gymn, gy); gymx = fmaxf(gymx, gy);
    }
    #pragma unroll
    for (int t = 0; t < 6; ++t){ Aw[t] = Bw[t]; Bw[t] = Cw[t]; }
  }
  for (int off = 32; off; off >>= 1){
    gxmn = fminf(gxmn, __shfl_down(gxmn, off));
    gxmx = fmaxf(gxmx, __shfl_down(gxmx, off));
    gymn = fminf(gymn, __shfl_down(gymn, off));
    gymx = fmaxf(gymx, __shfl_down(gymx, off));
  }
  if (tid == 0){
    atomicMin(&mm[c],      fkey(gxmn));
    atomicMin(&mm[16+c],   fkey(gymn));
    atomicMax(&mm[32+c],   fkey(gxmx));
    atomicMax(&mm[48+c],   fkey(gymx));
  }
}

// ---- main: 2 independent waves / block (128 threads), 64 px each ----
// (r17 configuration — measured best. r12-r19 established ~255us as this
// structure's floor: all ILP/TLP/register/LDS/memory-path variations were
// neutral or regressions.)
__global__ __launch_bounds__(128) void k_main(
    const float* __restrict__ x, const float* __restrict__ mrand,
    const unsigned* __restrict__ mm,
    const _Float16* __restrict__ w1kh, const _Float16* __restrict__ w1kl,
    const _Float16* __restrict__ w1k1h, const _Float16* __restrict__ w1k1l,
    const _Float16* __restrict__ w2h, const float* __restrict__ w2f,
    const float* __restrict__ b1,
    float* __restrict__ out, float* __restrict__ alpha_new,
    unsigned char* __restrict__ premask)
{
  // per-wave slab: 16 chunks of 16B per row, XOR-swizzled (chunk ^ (px&15))
  // y: chunks 0..5 hi, 6..11 lo; after consumption row is reused for h.
  __shared__ __align__(16) _Float16 yl[2][64][128];   // 32 KB
  __shared__ float amn_x[16], inv_x[16], amn_y[16], inv_y[16];

  const int tid  = threadIdx.x;
  const int wvid = tid >> 6;
  const int lane = tid & 63;
  // XCD swizzle (r11-proven): contiguous 2048-block chunk per XCD
  const int blk  = blockIdx.x;
  const int bswz = (blk & 7)*2048 + (blk >> 3);
  const int half = bswz & 1;
  const int rowid = bswz >> 1;                 // b*H + i
  const int i = rowid & 255, b = rowid >> 8;
  const int j0 = half*128 + wvid*64;           // per-wave 64-px window
  const int q = lane >> 4, n16 = lane & 15;

  if (lane < 16){                              // BOTH waves: benign same-value race
    int c = lane;
    float mn = fabsf(fkeyinv(mm[c]));
    float mx = fabsf(fkeyinv(mm[32+c]));
    float dv = mn + mx;
    amn_x[c] = mn; inv_x[c] = (dv == 0.f) ? 1.f : 1.f/dv;
    mn = fabsf(fkeyinv(mm[16+c]));
    mx = fabsf(fkeyinv(mm[48+c]));
    dv = mn + mx;
    amn_y[c] = mn; inv_y[c] = (dv == 0.f) ? 1.f : 1.f/dv;
  }
  // wave-private LDS ops are program-ordered -> no barrier needed

  // ---- stencil: direct 9-tap loads (L1 absorbs overlap; r10-proven) ----
  {
    const float* xb = x + (size_t)b * C * HW;
    const int j = j0 + lane;
    const int key = lane & 15;
    const int im = i-1, ipp = i+1;
    const bool iu = im >= 0, id = ipp < H, jl = j > 0, jr = j < W-1;
    #pragma unroll
    for (int hp = 0; hp < 2; ++hp){
      float xv[8], lv[8], mv[8];
      #pragma unroll
      for (int cc = 0; cc < 8; ++cc){
        const int c = hp*8 + cc;
        const float* pc = xb + (size_t)c * HW;
        const float* r0 = pc + (size_t)im*W;
        const float* r1 = pc + (size_t)i*W;
        const float* r2 = pc + (size_t)ipp*W;
        float v00 = (iu&&jl) ? r0[j-1] : 0.f;
        float v01 =  iu      ? r0[j]   : 0.f;
        float v02 = (iu&&jr) ? r0[j+1] : 0.f;
        float v10 =  jl      ? r1[j-1] : 0.f;
        float v11 =            r1[j];
        float v12 =  jr      ? r1[j+1] : 0.f;
        float v20 = (id&&jl) ? r2[j-1] : 0.f;
        float v21 =  id      ? r2[j]   : 0.f;
        float v22 = (id&&jr) ? r2[j+1] : 0.f;
        float gx = (v02 - v00 + 2.f*(v12 - v10) + v22 - v20) * 0.125f;
        float gy = (v20 - v00 + 2.f*(v21 - v01) + v22 - v02) * 0.125f;
        float gl = (v01 + v10 + v12 + v21 - 4.f*v11) * 0.125f;
        float gxn = (gx + amn_x[c]) * inv_x[c];
        float gyn = (gy + amn_y[c]) * inv_y[c];
        xv[cc] = v11;
        lv[cc] = gl;
        mv[cc] = sqrtf(gxn*gxn + gyn*gyn);
        if (hp == 0 && cc == 3){
          float pre3 = fmaxf(fmaxf(fmaxf(v00,v01),fmaxf(v02,v10)),
                       fmaxf(fmaxf(v11,v12),fmaxf(fmaxf(v20,v21),v22)));
          premask[(size_t)b*HW + (size_t)i*W + j] = (pre3 > 0.1f) ? 1 : 0;
        }
      }
      f16x8 vh, vl;
      #pragma unroll
      for (int e = 0; e < 8; ++e){ _Float16 h=(_Float16)xv[e]; vh[e]=h; vl[e]=(_Float16)(xv[e]-(float)h); }
      *(f16x8*)&yl[wvid][lane][((hp     ) ^ key)*8] = vh;
      *(f16x8*)&yl[wvid][lane][((6+hp   ) ^ key)*8] = vl;
      #pragma unroll
      for (int e = 0; e < 8; ++e){ _Float16 h=(_Float16)lv[e]; vh[e]=h; vl[e]=(_Float16)(lv[e]-(float)h); }
      *(f16x8*)&yl[wvid][lane][((2+hp   ) ^ key)*8] = vh;
      *(f16x8*)&yl[wvid][lane][((8+hp   ) ^ key)*8] = vl;
      #pragma unroll
      for (int e = 0; e < 8; ++e){ _Float16 h=(_Float16)mv[e]; vh[e]=h; vl[e]=(_Float16)(mv[e]-(float)h); }
      *(f16x8*)&yl[wvid][lane][((4+hp   ) ^ key)*8] = vh;
      *(f16x8*)&yl[wvid][lane][((10+hp  ) ^ key)*8] = vl;
    }
  }

  // ---- resident fragments: A1 x32 hi/lo (64 VGPR) + A2 hi (16 VGPR) ----
  f16x8 A1h[8], A1l[8];
  #pragma unroll
  for (int ot = 0; ot < 8; ++ot){
    A1h[ot] = *(const f16x8*)(w1kh + ot*512 + lane*8);
    A1l[ot] = *(const f16x8*)(w1kl + ot*512 + lane*8);
  }
  f16x8 A2h[4];
  #pragma unroll
  for (int s = 0; s < 4; ++s)
    A2h[s] = *(const f16x8*)(w2h + s*512 + lane*8);

  const size_t rowbase = (size_t)b*C*HW + (size_t)i*W;
  const size_t abase   = (size_t)b*HW + (size_t)i*W;
  const float* mr_row  = mrand + abase + j0;
  const float* w2r3    = w2f + 3*HID;

  // ---- 4 groups of 16 pixels ----
  #pragma unroll 1
  for (int g = 0; g < 4; ++g){
    const int pl = g*16 + n16;                // local pixel / LDS row
    const int key = n16;                      // = pl & 15
    _Float16* yr = yl[wvid][pl];
    f16x8 Bh0 = *(const f16x8*)&yr[(( q          ) ^ key)*8];
    f16x8 Bl0 = *(const f16x8*)&yr[(( 6+q        ) ^ key)*8];
    f16x4 Bh1 = *(const f16x4*)(&yr[(( 4+(q>>1)  ) ^ key)*8] + 4*(q&1));
    f16x4 Bl1 = *(const f16x4*)(&yr[((10+(q>>1)  ) ^ key)*8] + 4*(q&1));

    // GEMM1: h = relu(w1*y + b1); 4-product hi/lo over K=32 (x32) + K=16 (x16)
    // h written straight back into the (now dead) LDS row as the transpose.
    float partial3 = 0.f;
    #pragma unroll
    for (int ot = 0; ot < 8; ++ot){
      f16x4 A1h1 = *(const f16x4*)(w1k1h + ot*256 + lane*4);  // L1-hot 4KB
      f16x4 A1l1 = *(const f16x4*)(w1k1l + ot*256 + lane*4);
      f32x4 acc = *(const f32x4*)(b1 + 16*ot + 4*q);          // L1-hot
      acc = __builtin_amdgcn_mfma_f32_16x16x32_f16(A1h[ot], Bh0, acc, 0, 0, 0);
      acc = __builtin_amdgcn_mfma_f32_16x16x32_f16(A1h[ot], Bl0, acc, 0, 0, 0);
      acc = __builtin_amdgcn_mfma_f32_16x16x32_f16(A1l[ot], Bh0, acc, 0, 0, 0);
      acc = __builtin_amdgcn_mfma_f32_16x16x32_f16(A1l[ot], Bl0, acc, 0, 0, 0);
      acc = __builtin_amdgcn_mfma_f32_16x16x16f16(A1h1, Bh1, acc, 0, 0, 0);
      acc = __builtin_amdgcn_mfma_f32_16x16x16f16(A1h1, Bl1, acc, 0, 0, 0);
      acc = __builtin_amdgcn_mfma_f32_16x16x16f16(A1l1, Bh1, acc, 0, 0, 0);
      acc = __builtin_amdgcn_mfma_f32_16x16x16f16(A1l1, Bl1, acc, 0, 0, 0);
      float h0 = fmaxf(acc[0],0.f), h1 = fmaxf(acc[1],0.f);
      float h2 = fmaxf(acc[2],0.f), h3 = fmaxf(acc[3],0.f);
      // exact fp32 alpha path: partial dot with w2 row 3 (L1-hot 512B)
      f32x4 w3 = *(const f32x4*)(w2r3 + 16*ot + 4*q);
      partial3 = fmaf(w3[0],h0, fmaf(w3[1],h1, fmaf(w3[2],h2, fmaf(w3[3],h3, partial3))));
      // h[o=16ot+4q+r][px=pl] -> row pl, chunk (2ot+(q>>1))^key, half q&1
      f16x4 hv;
      hv[0]=(_Float16)h0; hv[1]=(_Float16)h1; hv[2]=(_Float16)h2; hv[3]=(_Float16)h3;
      *(f16x4*)(&yr[(((2*ot + (q>>1)) ^ key)*8) + 4*(q&1)]) = hv;
    }
    // reduce partial3 across the 4 q-groups (within the wave)
    partial3 += __shfl_xor(partial3, 16);
    partial3 += __shfl_xor(partial3, 32);      // dx[3] for pixel pl, all lanes

    // GEMM2 (hi-only): dx = w2h * h; B read back from the transposed row
    f32x4 d2 = {0.f, 0.f, 0.f, 0.f};
    #pragma unroll
    for (int s = 0; s < 4; ++s){
      f16x8 B2 = *(const f16x8*)&yr[((4*s + q) ^ key)*8];
      d2 = __builtin_amdgcn_mfma_f32_16x16x32_f16(A2h[s], B2, d2, 0, 0, 0);
    }

    // epilogue: x re-read from global (L1/L2-hot under XCD swizzle; r13-proven)
    const float fire = (mr_row[pl] <= 0.5f) ? 1.f : 0.f;
    float a3v = 0.f;
    #pragma unroll
    for (int r = 0; r < 4; ++r){
      const int c = 4*q + r;
      const size_t idx = rowbase + (size_t)c*HW + (j0 + pl);
      const float xv = x[idx];
      const float dxv = (c == 3) ? partial3 : d2[r];
      const float val = xv + dxv*fire;
      out[idx] = val;
      if (c == 3) a3v = val;
    }
    if (q == 0) alpha_new[abase + j0 + pl] = a3v;
  }
}

// ---- life: pre-mask (from k_main) AND pooled(alpha_new) > 0.1 ----
__global__ __launch_bounds__(256) void k_life(
    const float* __restrict__ alpha_new,
    const unsigned char* __restrict__ premask,
    float* __restrict__ out)
{
  __shared__ float lds[258];
  const int i = blockIdx.x & 255, b = blockIdx.x >> 8;
  const int j = threadIdx.x;
  const float* an = alpha_new + (size_t)b*HW;
  float m = an[(size_t)i*W + j];
  if (i > 0)   m = fmaxf(m, an[(size_t)(i-1)*W + j]);
  if (i < 255) m = fmaxf(m, an[(size_t)(i+1)*W + j]);
  if (j == 0){ lds[0] = 0.f; lds[257] = 0.f; }
  lds[j+1] = m;
  __syncthreads();
  float pooled = fmaxf(fmaxf(lds[j], lds[j+1]), lds[j+2]);
  bool life = (premask[(size_t)b*HW + (size_t)i*W + j] != 0) && (pooled > 0.1f);
  if (!life){
    size_t px = (size_t)b*C*HW + (size_t)i*W + j;
    #pragma unroll
    for (int c = 0; c < 16; ++c) out[px + (size_t)c*HW] = 0.f;
  }
}

extern "C" void kernel_launch(void* const* d_in, const int* in_sizes, int n_in,
                              void* d_out, int out_size, void* d_ws, size_t ws_size,
                              hipStream_t stream) {
  const float* x  = (const float*)d_in[0];
  const float* w1 = (const float*)d_in[1];
  const float* b1 = (const float*)d_in[2];
  const float* w2 = (const float*)d_in[3];
  const float* mr = (const float*)d_in[4];

  char* ws = (char*)d_ws;
  unsigned* mm          = (unsigned*)ws;                          // 256 B
  float* alpha_n        = (float*)(ws + 256);                     // 8 MB
  unsigned char* pmask  = (unsigned char*)(ws + 256 + 8388608);   // 2 MB
  char* wb              = ws + 256 + 8388608 + 2097152;
  _Float16* w1kh  = (_Float16*)(wb);                              // 8 KB
  _Float16* w1kl  = (_Float16*)(wb + 8192);                       // 8 KB
  _Float16* w1k1h = (_Float16*)(wb + 16384);                      // 4 KB
  _Float16* w1k1l = (_Float16*)(wb + 20480);                      // 4 KB
  _Float16* w2h   = (_Float16*)(wb + 24576);                      // 4 KB
  float* out = (float*)d_out;

  (void)hipMemsetAsync(mm, 0xFF, 128, stream);                // mins -> +inf key
  (void)hipMemsetAsync((char*)mm + 128, 0x00, 128, stream);   // maxs -> -inf key
  k_pm  <<<NMM + 128, 64, 0, stream>>>(x, w1, w2, mm, w1kh, w1kl,
                                       w1k1h, w1k1l, w2h);
  k_main<<<B*H*2, 128, 0, stream>>>(x, mr, mm, w1kh, w1kl, w1k1h, w1k1l,
                                    w2h, w2, b1, out, alpha_n, pmask);
  k_life<<<B*H, 256, 0, stream>>>(alpha_n, pmask, out);
}